// Round 5
// baseline (1275.382 us; speedup 1.0000x reference)
//
#include <hip/hip_runtime.h>
#include <math.h>

#define H 1024
#define V 50257
#define L 512
#define NBLK 1024
#define NTHR 256
#define SROWS 6      // vocab rows prefetched to LDS per block

// ws layout (float indices)
#define WS_CTR    0      // 40 ints: 5 barriers x 8 sub-counters (memset 160B each call)
#define WS_LOGITS 64     // 512 attn logits
#define WS_ATTN   576    // 1024 attn_applied (atomic accum; zeroed by blocks 512-515 in P1)
#define WS_X      1600   // 1024 combine output
#define WS_H      2624   // 1024 new h
#define WS_PART   3648   // 1024 per-block vocab exp-sums
#define WS_VLOG   4672   // 50257 vocab logits

#define AS1 __attribute__((address_space(1)))
#define AS3 __attribute__((address_space(3)))

__device__ __forceinline__ float wave_sum(float v) {
    for (int o = 32; o > 0; o >>= 1) v += __shfl_down(v, o, 64);
    return v;
}
__device__ __forceinline__ float sigf(float x) { return 1.0f / (1.0f + expf(-x)); }
__device__ __forceinline__ float dot4(float4 a, float4 b) {
    return a.x * b.x + a.y * b.y + a.z * b.z + a.w * b.w;
}
__device__ __forceinline__ void gld_lds16(const float* g, float* l) {
    __builtin_amdgcn_global_load_lds((const AS1 void*)g, (AS3 void*)l, 16, 0, 0);
}

// Correct all-block barrier:
//  - EVERY wave: __threadfence() (release: s_waitcnt vmcnt(0) + buffer_wbl2)
//    so all stores/atomics/staging-loads of all waves are drained & written back.
//  - t0 arrives on one of 8 spread counters, spins until all NBLK arrived.
//  - EVERY wave: __threadfence() (acquire: buffer_inv) so subsequent plain
//    loads miss stale L1/L2 and read the coherent point.
__device__ __forceinline__ void gbarrier(int* ctr, int bid) {
    __threadfence();
    __syncthreads();
    if (threadIdx.x == 0) {
        __hip_atomic_fetch_add(&ctr[bid & 7], 1, __ATOMIC_RELAXED, __HIP_MEMORY_SCOPE_AGENT);
        int sum;
        do {
            sum = 0;
#pragma unroll
            for (int i = 0; i < 8; ++i)
                sum += __hip_atomic_load(&ctr[i], __ATOMIC_RELAXED, __HIP_MEMORY_SCOPE_AGENT);
            if (sum < NBLK) __builtin_amdgcn_s_sleep(4);
        } while (sum < NBLK);
    }
    __syncthreads();
    __threadfence();
}

__global__ __launch_bounds__(NTHR, 4) void fused_decoder(
        const int* __restrict__ tok, const float* __restrict__ hidden,
        const float* __restrict__ enc, const float* __restrict__ emb,
        const float* __restrict__ attn_W, const float* __restrict__ attn_b,
        const float* __restrict__ comb_W, const float* __restrict__ comb_b,
        const float* __restrict__ W_ih, const float* __restrict__ W_hh,
        const float* __restrict__ b_ih, const float* __restrict__ b_hh,
        const float* __restrict__ out_W, const float* __restrict__ out_b,
        float* __restrict__ ws, float* __restrict__ out) {
    const int bid = blockIdx.x, t = threadIdx.x;
    const int w = t >> 6, l = t & 63;
    int* ctr = (int*)(ws + WS_CTR);

    __shared__ float4 staged4[SROWS * 256];  // 24 KB
    __shared__ float red[4];
    __shared__ float wl[16];
    __shared__ float gsh[4];
    __shared__ float bmbs[2];
    __shared__ float lsh;

    // vocab row range: V = 1024*49 + 81
    const int row0 = bid * 49 + (bid < 81 ? bid : 81);
    const int cnt  = 49 + (bid < 81 ? 1 : 0);

    const size_t token = (size_t)tok[0];
    const float4* ev4 = (const float4*)(emb + token * H);
    const float4* hv4 = (const float4*)hidden;

    // ---- P1: attn logits (blocks 0-511); blocks 512-515 zero attn accum ----
    if (bid < 512) {
        const float4* rw = (const float4*)(attn_W + (size_t)bid * 2 * H);
        float acc = dot4(ev4[t], rw[t]) + dot4(hv4[t], rw[256 + t]);
        float s = wave_sum(acc);
        if (l == 0) red[w] = s;
        __syncthreads();
        if (t == 0)
            ws[WS_LOGITS + bid] = red[0] + red[1] + red[2] + red[3] + attn_b[bid];
    } else if (bid < 516) {
        ws[WS_ATTN + (bid - 512) * 256 + t] = 0.0f;
    }
    gbarrier(ctr + 0 * 8, bid);

    // ---- P2: attn softmax (max-sub) + attn_applied (blocks 0-127) ----
    if (bid < 128) {
        int jb = bid >> 5, lc = bid & 31;
        float v0 = ws[WS_LOGITS + t];
        float v1 = ws[WS_LOGITS + 256 + t];
        float m = fmaxf(v0, v1);
        for (int o = 32; o > 0; o >>= 1) m = fmaxf(m, __shfl_down(m, o, 64));
        if (l == 0) red[w] = m;
        __syncthreads();
        if (t == 0) bmbs[0] = fmaxf(fmaxf(red[0], red[1]), fmaxf(red[2], red[3]));
        __syncthreads();
        float bm = bmbs[0];
        float e = expf(v0 - bm) + expf(v1 - bm);
        float s = wave_sum(e);
        if (l == 0) red[w] = s;
        __syncthreads();
        if (t == 0) bmbs[1] = red[0] + red[1] + red[2] + red[3];
        __syncthreads();
        float bs = bmbs[1];
        int l0 = lc * 16;
        if (t < 16) wl[t] = expf(ws[WS_LOGITS + l0 + t] - bm) / bs;
        if (lc == 0 && t < 128)
            out[V + 2 * H + jb * 128 + t] = expf(ws[WS_LOGITS + jb * 128 + t] - bm) / bs;
        __syncthreads();
        int j = jb * 256 + t;
        float acc = 0.f;
#pragma unroll
        for (int i = 0; i < 16; ++i)
            acc += wl[i] * enc[(size_t)(l0 + i) * H + j];
        atomicAdd(&ws[WS_ATTN + j], acc);
    }
    gbarrier(ctr + 1 * 8, bid);

    // ---- P3: combine + relu (blocks 0-255, wave per row) ----
    if (bid < 256) {
        int r = bid * 4 + w;
        const float4* a4 = (const float4*)(ws + WS_ATTN);
        const float4* cw = (const float4*)comb_W;
        float acc = 0.f;
#pragma unroll
        for (int i = 0; i < 4; ++i) {
            acc += dot4(cw[(size_t)r * 512 + i * 64 + l], ev4[i * 64 + l]);
            acc += dot4(cw[(size_t)r * 512 + 256 + i * 64 + l], a4[i * 64 + l]);
        }
        float s = wave_sum(acc);
        if (l == 0) ws[WS_X + r] = fmaxf(s + comb_b[r], 0.0f);
    }
    // issue LDS prefetch of first SROWS vocab rows; the barrier fence's
    // vmcnt(0) completes them while blocks spin / P4 runs.
#pragma unroll
    for (int r = 0; r < SROWS; ++r) {
        const float* src = out_W + (size_t)(row0 + r) * H + w * 256 + l * 4;
        gld_lds16(src, (float*)&staged4[r * 256 + w * 64]);
    }
    gbarrier(ctr + 2 * 8, bid);

    // ---- P4: gates + LSTM pointwise (all blocks; block = unit bid; wave = gate) ----
    {
        const float4* x4p = (const float4*)(ws + WS_X);
        const float4* wi = (const float4*)W_ih;
        const float4* wh = (const float4*)W_hh;
        int row = w * H + bid;
        float acc = 0.f;
#pragma unroll
        for (int i = 0; i < 4; ++i) {
            acc += dot4(wi[(size_t)row * 256 + i * 64 + l], x4p[i * 64 + l]);
            acc += dot4(wh[(size_t)row * 256 + i * 64 + l], hv4[i * 64 + l]);
        }
        float s = wave_sum(acc);
        if (l == 0) gsh[w] = s + b_ih[row] + b_hh[row];
        __syncthreads();
        if (t == 0) {
            float c0 = hidden[bid];
            float c = sigf(gsh[1]) * c0 + sigf(gsh[0]) * tanhf(gsh[2]);
            float hh = sigf(gsh[3]) * tanhf(c);
            ws[WS_H + bid] = hh;
            out[V + bid] = hh;
            out[V + H + bid] = c;
        }
    }
    gbarrier(ctr + 3 * 8, bid);

    // ---- P5: vocab logits (SROWS from LDS, rest HBM) + per-block exp-sum ----
    {
        const float4* h4 = (const float4*)(ws + WS_H);
        float4 hr[4];
#pragma unroll
        for (int i = 0; i < 4; ++i) hr[i] = h4[i * 64 + l];
        const float4* ow = (const float4*)out_W;
        float es = 0.f;
        int wq = (cnt + 3) >> 2;
        int jb = w * wq;
        int je = jb + wq < cnt ? jb + wq : cnt;
        for (int k = jb; k < je; k += 2) {
            bool has1 = (k + 1 < je);
            int kk1 = has1 ? k + 1 : k;
            int r0 = row0 + k, r1 = row0 + kk1;
            float a0 = 0.f, a1 = 0.f;
            if (kk1 < SROWS) {  // wave 0 only; SROWS even so never mixed
#pragma unroll
                for (int i = 0; i < 4; ++i) {
                    a0 += dot4(staged4[k * 256 + i * 64 + l], hr[i]);
                    a1 += dot4(staged4[kk1 * 256 + i * 64 + l], hr[i]);
                }
            } else {
                const float4* q0 = ow + (size_t)r0 * 256;
                const float4* q1 = ow + (size_t)r1 * 256;
#pragma unroll
                for (int i = 0; i < 4; ++i) {
                    a0 += dot4(q0[i * 64 + l], hr[i]);
                    a1 += dot4(q1[i * 64 + l], hr[i]);
                }
            }
            float s0 = wave_sum(a0);
            float s1 = wave_sum(a1);
            if (l == 0) {
                float lg0 = s0 + out_b[r0];
                ws[WS_VLOG + r0] = lg0;
                es += expf(lg0);
                if (has1) {
                    float lg1 = s1 + out_b[r1];
                    ws[WS_VLOG + r1] = lg1;
                    es += expf(lg1);
                }
            }
        }
        if (l == 0) red[w] = es;
        __syncthreads();
        if (t == 0) ws[WS_PART + bid] = red[0] + red[1] + red[2] + red[3];
    }
    gbarrier(ctr + 4 * 8, bid);

    // ---- P6: redundant deterministic LSE reduce + write own slice ----
    {
        float ps = ws[WS_PART + t] + ws[WS_PART + t + 256]
                 + ws[WS_PART + t + 512] + ws[WS_PART + t + 768];
        float s = wave_sum(ps);
        if (l == 0) red[w] = s;
        __syncthreads();
        if (t == 0) lsh = logf(red[0] + red[1] + red[2] + red[3]);
        __syncthreads();
        float lse = lsh;
        for (int i = t; i < cnt; i += NTHR)
            out[row0 + i] = ws[WS_VLOG + row0 + i] - lse;
    }
}

extern "C" void kernel_launch(void* const* d_in, const int* in_sizes, int n_in,
                              void* d_out, int out_size, void* d_ws, size_t ws_size,
                              hipStream_t stream) {
    const int*   tok     = (const int*)d_in[0];
    const float* hidden  = (const float*)d_in[1];
    const float* enc     = (const float*)d_in[2];
    const float* emb     = (const float*)d_in[3];
    const float* attn_W  = (const float*)d_in[4];
    const float* attn_b  = (const float*)d_in[5];
    const float* comb_W  = (const float*)d_in[6];
    const float* comb_b  = (const float*)d_in[7];
    const float* W_ih    = (const float*)d_in[8];
    const float* W_hh    = (const float*)d_in[9];
    const float* b_ih    = (const float*)d_in[10];
    const float* b_hh    = (const float*)d_in[11];
    const float* out_W   = (const float*)d_in[12];
    const float* out_b   = (const float*)d_in[13];
    float* out = (float*)d_out;
    float* ws  = (float*)d_ws;

    // zero the 5x8 barrier counters each replay
    hipMemsetAsync(ws, 0, 160, stream);
    fused_decoder<<<NBLK, NTHR, 0, stream>>>(tok, hidden, enc, emb, attn_W, attn_b,
                                             comb_W, comb_b, W_ih, W_hh, b_ih, b_hh,
                                             out_W, out_b, ws, out);
}

// Round 6
// 195.174 us; speedup vs baseline: 6.5346x; 6.5346x over previous
//
#include <hip/hip_runtime.h>
#include <math.h>

#define H 1024
#define V 50257
#define L 512
#define NB_AB 128
#define NB_EF 1024

// ws float indices
#define WS_FLAGA 0      // int: kAB arrival counter
#define WS_FLAGV 1      // int: kEF arrival counter
#define WS_DENA  2      // float: attn softmax denominator
#define WS_DENV  3      // float: vocab exp-sum
#define WS_ATTN  64     // 1024 attn_applied (atomicAdd accum)
#define WS_X     1600   // 1024 combine output
#define WS_H     2624   // 1024 new h
#define MEMSET_BYTES 4352   // zeroes [0, 1088) floats: flags+denoms+attn accum

__device__ __forceinline__ float wave_sum(float v) {
    for (int o = 32; o > 0; o >>= 1) v += __shfl_down(v, o, 64);
    return v;
}
__device__ __forceinline__ float sigf(float x) { return 1.0f / (1.0f + expf(-x)); }
__device__ __forceinline__ float dot4(float4 a, float4 b) {
    return a.x * b.x + a.y * b.y + a.z * b.z + a.w * b.w;
}

// scalar-flag arrive + spin: partial (scalar) atomicAdd, RELEASE flag add,
// RELAXED single-address poll, RELAXED scalar read after release.
// All traffic is agent-scope atomics to one coherent point - no fences,
// no per-element atomic data, no cache maintenance.
__device__ __forceinline__ float arrive_and_wait_sum(float* den, int* flag,
                                                     float partial, int nblk) {
    __hip_atomic_fetch_add(den, partial, __ATOMIC_RELAXED, __HIP_MEMORY_SCOPE_AGENT);
    __hip_atomic_fetch_add(flag, 1, __ATOMIC_RELEASE, __HIP_MEMORY_SCOPE_AGENT);
    while (__hip_atomic_load(flag, __ATOMIC_RELAXED, __HIP_MEMORY_SCOPE_AGENT) < nblk)
        __builtin_amdgcn_s_sleep(8);
    return __hip_atomic_load(den, __ATOMIC_RELAXED, __HIP_MEMORY_SCOPE_AGENT);
}

// kAB: attn logits + softmax + attn_applied in ONE kernel. grid 128 x 256.
// Wave w computes logit r=bid*4+w (kept in LDS). Scalar exp-sum via flag
// protocol; weights computed locally; accum via plain atomicAdd.
__global__ __launch_bounds__(256) void kAB(const int* __restrict__ tok,
                                           const float* __restrict__ hidden,
                                           const float* __restrict__ enc,
                                           const float* __restrict__ emb,
                                           const float* __restrict__ attn_W,
                                           const float* __restrict__ attn_b,
                                           float* __restrict__ ws,
                                           float* __restrict__ out) {
    const int bid = blockIdx.x, t = threadIdx.x;
    const int w = t >> 6, l = t & 63;
    const size_t token = (size_t)tok[0];
    const float4* ev4 = (const float4*)(emb + token * H);
    const float4* hv4 = (const float4*)hidden;

    __shared__ float lg[4];    // this block's 4 logits
    __shared__ float wexp[4];  // this block's 4 softmax weights
    __shared__ float dsh;

    int r = bid * 4 + w;
    const float4* rw = (const float4*)(attn_W + (size_t)r * 2 * H);
    float acc = 0.f;
#pragma unroll
    for (int i = 0; i < 4; ++i) {
        acc += dot4(rw[i * 64 + l], ev4[i * 64 + l]);
        acc += dot4(rw[256 + i * 64 + l], hv4[i * 64 + l]);
    }
    float s = wave_sum(acc);
    if (l == 0) lg[w] = s + attn_b[r];
    __syncthreads();
    if (t == 0) {
        float p = expf(lg[0]) + expf(lg[1]) + expf(lg[2]) + expf(lg[3]);
        dsh = arrive_and_wait_sum((float*)&((int*)ws)[0] + WS_DENA,
                                  (int*)ws + WS_FLAGA, p, NB_AB);
    }
    __syncthreads();
    float denom = dsh;
    if (t < 4) {
        float wv = expf(lg[t]) / denom;
        wexp[t] = wv;
        out[V + 2 * H + bid * 4 + t] = wv;   // attn_weights output
    }
    __syncthreads();
    // attn_applied: this block's 4 encoder rows x all 1024 columns
    int l0 = bid * 4;
#pragma unroll
    for (int jj = 0; jj < 4; ++jj) {
        int j = jj * 256 + t;
        float a = 0.f;
#pragma unroll
        for (int i = 0; i < 4; ++i)
            a += wexp[i] * enc[(size_t)(l0 + i) * H + j];
        atomicAdd(&ws[WS_ATTN + j], a);
    }
}

// kC: x[r] = relu(dot(concat(embedded, attn_applied), comb_W[r]) + comb_b[r])
// grid 256 x 256, wave per row.
__global__ void kC_combine(const int* __restrict__ tok,
                           const float* __restrict__ emb,
                           const float* __restrict__ comb_W,
                           const float* __restrict__ comb_b,
                           float* __restrict__ ws) {
    int t = threadIdx.x;
    int w = t >> 6, l = t & 63;
    size_t token = (size_t)tok[0];
    const float4* ev4 = (const float4*)(emb + token * H);
    const float4* a4 = (const float4*)(ws + WS_ATTN);
    int r = blockIdx.x * 4 + w;
    const float4* cw = (const float4*)comb_W;
    float acc = 0.f;
#pragma unroll
    for (int i = 0; i < 4; ++i) {
        acc += dot4(cw[(size_t)r * 512 + i * 64 + l], ev4[i * 64 + l]);
        acc += dot4(cw[(size_t)r * 512 + 256 + i * 64 + l], a4[i * 64 + l]);
    }
    float s = wave_sum(acc);
    if (l == 0) ws[WS_X + r] = fmaxf(s + comb_b[r], 0.0f);
}

// kD: gates + LSTM pointwise. grid 512 x 256 (R4-proven structure).
__global__ void kD_gates_lstm(const float* __restrict__ hidden,
                              const float* __restrict__ W_ih,
                              const float* __restrict__ W_hh,
                              const float* __restrict__ b_ih,
                              const float* __restrict__ b_hh,
                              float* __restrict__ ws,
                              float* __restrict__ out) {
    int t = threadIdx.x;
    int w = t >> 6, l = t & 63;
    __shared__ float4 xs[256], hs[256];
    xs[t] = ((const float4*)(ws + WS_X))[t];
    hs[t] = ((const float4*)hidden)[t];
    __syncthreads();
    int u = w >> 1, gp = w & 1;
    int n = blockIdx.x * 2 + u;
    int row0 = (gp * 2) * H + n;
    int row1 = (gp * 2 + 1) * H + n;
    const float4* wi = (const float4*)W_ih;
    const float4* wh = (const float4*)W_hh;
    float a0 = 0.f, a1 = 0.f;
#pragma unroll
    for (int i = 0; i < 4; ++i) {
        float4 x4 = xs[i * 64 + l], h4 = hs[i * 64 + l];
        a0 += dot4(wi[(size_t)row0 * 256 + i * 64 + l], x4);
        a0 += dot4(wh[(size_t)row0 * 256 + i * 64 + l], h4);
        a1 += dot4(wi[(size_t)row1 * 256 + i * 64 + l], x4);
        a1 += dot4(wh[(size_t)row1 * 256 + i * 64 + l], h4);
    }
    float s0 = wave_sum(a0);
    float s1 = wave_sum(a1);
    __shared__ float gsh[2][4];
    if (l == 0) {
        gsh[u][gp * 2]     = s0 + b_ih[row0] + b_hh[row0];
        gsh[u][gp * 2 + 1] = s1 + b_ih[row1] + b_hh[row1];
    }
    __syncthreads();
    if (t < 2) {
        int nn = blockIdx.x * 2 + t;
        float gi = gsh[t][0], gf = gsh[t][1], gg = gsh[t][2], go = gsh[t][3];
        float c0 = hidden[nn];
        float c = sigf(gf) * c0 + sigf(gi) * tanhf(gg);
        float h = sigf(go) * tanhf(c);
        ws[WS_H + nn] = h;
        out[V + nn] = h;
        out[V + H + nn] = c;
    }
}

// kEF: vocab logits (kept in LDS) + scalar exp-sum flag protocol + final
// log-softmax write. grid EXACTLY 1024 x 256 with launch_bounds(256,4):
// 4 blocks/CU x 256 CUs = 1024 resident -> spin is deadlock-free.
__global__ __launch_bounds__(256, 4) void kEF(const float* __restrict__ out_W,
                                              const float* __restrict__ out_b,
                                              float* __restrict__ ws,
                                              float* __restrict__ out) {
    const int bid = blockIdx.x, t = threadIdx.x;
    const int w = t >> 6, l = t & 63;
    // V = 1024*49 + 81
    const int row0 = bid * 49 + (bid < 81 ? bid : 81);
    const int cnt  = 49 + (bid < 81 ? 1 : 0);

    __shared__ float slog[52];
    __shared__ float red[4];
    __shared__ float lsh;

    const float4* h4 = (const float4*)(ws + WS_H);
    float4 hr[4];
#pragma unroll
    for (int i = 0; i < 4; ++i) hr[i] = h4[i * 64 + l];

    const float4* ow = (const float4*)out_W;
    float es = 0.f;
    for (int k = w; k < cnt; k += 4) {
        int r = row0 + k;
        const float4* q = ow + (size_t)r * 256;
        float acc = 0.f;
#pragma unroll
        for (int i = 0; i < 4; ++i)
            acc += dot4(q[i * 64 + l], hr[i]);
        float s = wave_sum(acc);
        if (l == 0) {
            float lg = s + out_b[r];
            slog[k] = lg;
            es += expf(lg);
        }
    }
    if (l == 0) red[w] = es;
    __syncthreads();
    if (t == 0) {
        float p = red[0] + red[1] + red[2] + red[3];
        float S = arrive_and_wait_sum((float*)&((int*)ws)[0] + WS_DENV,
                                      (int*)ws + WS_FLAGV, p, NB_EF);
        lsh = logf(S);
    }
    __syncthreads();
    float lse = lsh;
    for (int i = t; i < cnt; i += 256)
        out[row0 + i] = slog[i] - lse;
}

extern "C" void kernel_launch(void* const* d_in, const int* in_sizes, int n_in,
                              void* d_out, int out_size, void* d_ws, size_t ws_size,
                              hipStream_t stream) {
    const int*   tok     = (const int*)d_in[0];
    const float* hidden  = (const float*)d_in[1];
    const float* enc     = (const float*)d_in[2];
    const float* emb     = (const float*)d_in[3];
    const float* attn_W  = (const float*)d_in[4];
    const float* attn_b  = (const float*)d_in[5];
    const float* comb_W  = (const float*)d_in[6];
    const float* comb_b  = (const float*)d_in[7];
    const float* W_ih    = (const float*)d_in[8];
    const float* W_hh    = (const float*)d_in[9];
    const float* b_ih    = (const float*)d_in[10];
    const float* b_hh    = (const float*)d_in[11];
    const float* out_W   = (const float*)d_in[12];
    const float* out_b   = (const float*)d_in[13];
    float* out = (float*)d_out;
    float* ws  = (float*)d_ws;

    // zero flags, scalar sums, attn accumulator each replay
    hipMemsetAsync(ws, 0, MEMSET_BYTES, stream);
    kAB<<<NB_AB, 256, 0, stream>>>(tok, hidden, enc, emb, attn_W, attn_b, ws, out);
    kC_combine<<<256, 256, 0, stream>>>(tok, emb, comb_W, comb_b, ws);
    kD_gates_lstm<<<512, 256, 0, stream>>>(hidden, W_ih, W_hh, b_ih, b_hh, ws, out);
    kEF<<<NB_EF, 256, 0, stream>>>(out_W, out_b, ws, out);
}

// Round 7
// 61.430 us; speedup vs baseline: 20.7615x; 3.1772x over previous
//
#include <hip/hip_runtime.h>
#include <math.h>

#define H 1024
#define V 50257
#define L 512

// ws float indices
#define WS_ATTN  0      // 1024 unnormalized attn accum (atomicAdd; memset-zeroed)
#define WS_DEN   1024   // 32 denom partials (plain stores, unique writer)
#define WS_E     1056   // 512 unnormalized exp(logit)
#define WS_X     1568   // 1024 combine output
#define WS_H     2592   // 1024 new h
#define WS_VLOG  3616   // 50257 vocab logits
#define WS_PART  53873  // 1280 per-block vocab exp-sums
#define MEMSET_BYTES 4096   // zeroes WS_ATTN [0,1024)

__device__ __forceinline__ float wave_sum(float v) {
    for (int o = 32; o > 0; o >>= 1) v += __shfl_down(v, o, 64);
    return v;
}
__device__ __forceinline__ float sigf(float x) { return 1.0f / (1.0f + expf(-x)); }
__device__ __forceinline__ float dot4(float4 a, float4 b) {
    return a.x * b.x + a.y * b.y + a.z * b.z + a.w * b.w;
}

// kAB: fused attn logits + (no-max) softmax numerators + unnormalized
// attn_applied. grid 128 x 256; block = (jb = col quarter, lc = 16-logit chunk).
// Each block redundantly computes its chunk's 16 logits (attn_W re-read x4,
// L3-warm). jb==0 blocks store e_l and the chunk denom partial (unique
// writers, plain stores). All blocks atomicAdd their column quarter (32-way
// contention per address -- the R2-proven level).
__global__ __launch_bounds__(256) void kAB(const int* __restrict__ tok,
                                           const float* __restrict__ hidden,
                                           const float* __restrict__ enc,
                                           const float* __restrict__ emb,
                                           const float* __restrict__ attn_W,
                                           const float* __restrict__ attn_b,
                                           float* __restrict__ ws) {
    const int bid = blockIdx.x, t = threadIdx.x;
    const int w = t >> 6, l = t & 63;
    const int jb = bid >> 5, lc = bid & 31;
    const size_t token = (size_t)tok[0];
    const float4* ev4 = (const float4*)(emb + token * H);
    const float4* hv4 = (const float4*)hidden;

    __shared__ float esh[16];

    // wave w computes logits r = lc*16 + w*4 + {0..3} (2 pairs, ILP)
#pragma unroll
    for (int p = 0; p < 2; ++p) {
        int r0 = lc * 16 + w * 4 + p * 2;
        int r1 = r0 + 1;
        const float4* rw0 = (const float4*)(attn_W + (size_t)r0 * 2 * H);
        const float4* rw1 = (const float4*)(attn_W + (size_t)r1 * 2 * H);
        float a0 = 0.f, a1 = 0.f;
#pragma unroll
        for (int i = 0; i < 4; ++i) {
            float4 e4 = ev4[i * 64 + l], h4 = hv4[i * 64 + l];
            a0 += dot4(rw0[i * 64 + l], e4) + dot4(rw0[256 + i * 64 + l], h4);
            a1 += dot4(rw1[i * 64 + l], e4) + dot4(rw1[256 + i * 64 + l], h4);
        }
        float s0 = wave_sum(a0);
        float s1 = wave_sum(a1);
        if (l == 0) {
            esh[w * 4 + p * 2]     = expf(s0 + attn_b[r0]);
            esh[w * 4 + p * 2 + 1] = expf(s1 + attn_b[r1]);
        }
    }
    __syncthreads();
    if (jb == 0) {
        if (t < 16) ws[WS_E + lc * 16 + t] = esh[t];
        if (t == 0) {
            float p = 0.f;
#pragma unroll
            for (int i = 0; i < 16; ++i) p += esh[i];
            ws[WS_DEN + lc] = p;   // unique writer per lc
        }
    }
    // unnormalized attn accumulate: this chunk's 16 enc rows x 256-col quarter
    int j = jb * 256 + t;
    float acc = 0.f;
#pragma unroll
    for (int i = 0; i < 16; ++i)
        acc += esh[i] * enc[(size_t)(lc * 16 + i) * H + j];
    atomicAdd(&ws[WS_ATTN + j], acc);
}

// kC: S = sum denom partials (redundant per block); x = relu(W_l@emb +
// (W_r@attn_unnorm)/S + b). Blocks 0,1 also write attn_weights = e/S.
// grid 256 x 256, wave per row.
__global__ __launch_bounds__(256) void kC_combine(const int* __restrict__ tok,
                                                  const float* __restrict__ emb,
                                                  const float* __restrict__ comb_W,
                                                  const float* __restrict__ comb_b,
                                                  float* __restrict__ ws,
                                                  float* __restrict__ out) {
    const int bid = blockIdx.x, t = threadIdx.x;
    const int w = t >> 6, l = t & 63;
    __shared__ float Ssh;
    float dv = (t < 32) ? ws[WS_DEN + t] : 0.f;
    if (w == 0) {
        float s = wave_sum(dv);
        if (t == 0) Ssh = s;
    }
    __syncthreads();
    float invS = 1.0f / Ssh;

    if (bid < 2) out[V + 2 * H + bid * 256 + t] = ws[WS_E + bid * 256 + t] * invS;

    const size_t token = (size_t)tok[0];
    const float4* ev4 = (const float4*)(emb + token * H);
    const float4* a4 = (const float4*)(ws + WS_ATTN);
    int r = bid * 4 + w;
    const float4* cw = (const float4*)comb_W;
    float aL = 0.f, aR = 0.f;
#pragma unroll
    for (int i = 0; i < 4; ++i) {
        aL += dot4(cw[(size_t)r * 512 + i * 64 + l], ev4[i * 64 + l]);
        aR += dot4(cw[(size_t)r * 512 + 256 + i * 64 + l], a4[i * 64 + l]);
    }
    float s = wave_sum(aL + aR * invS);
    if (l == 0) ws[WS_X + r] = fmaxf(s + comb_b[r], 0.0f);
}

// kD: gates + LSTM pointwise. grid 512 x 256 (R4-proven).
__global__ __launch_bounds__(256) void kD_gates_lstm(const float* __restrict__ hidden,
                                                     const float* __restrict__ W_ih,
                                                     const float* __restrict__ W_hh,
                                                     const float* __restrict__ b_ih,
                                                     const float* __restrict__ b_hh,
                                                     float* __restrict__ ws,
                                                     float* __restrict__ out) {
    int t = threadIdx.x;
    int w = t >> 6, l = t & 63;
    __shared__ float4 xs[256], hs[256];
    xs[t] = ((const float4*)(ws + WS_X))[t];
    hs[t] = ((const float4*)hidden)[t];
    __syncthreads();
    int u = w >> 1, gp = w & 1;
    int n = blockIdx.x * 2 + u;
    int row0 = (gp * 2) * H + n;
    int row1 = (gp * 2 + 1) * H + n;
    const float4* wi = (const float4*)W_ih;
    const float4* wh = (const float4*)W_hh;
    float a0 = 0.f, a1 = 0.f;
#pragma unroll
    for (int i = 0; i < 4; ++i) {
        float4 x4 = xs[i * 64 + l], h4 = hs[i * 64 + l];
        a0 += dot4(wi[(size_t)row0 * 256 + i * 64 + l], x4);
        a0 += dot4(wh[(size_t)row0 * 256 + i * 64 + l], h4);
        a1 += dot4(wi[(size_t)row1 * 256 + i * 64 + l], x4);
        a1 += dot4(wh[(size_t)row1 * 256 + i * 64 + l], h4);
    }
    float s0 = wave_sum(a0);
    float s1 = wave_sum(a1);
    __shared__ float gsh[2][4];
    if (l == 0) {
        gsh[u][gp * 2]     = s0 + b_ih[row0] + b_hh[row0];
        gsh[u][gp * 2 + 1] = s1 + b_ih[row1] + b_hh[row1];
    }
    __syncthreads();
    if (t < 2) {
        int nn = blockIdx.x * 2 + t;
        float gi = gsh[t][0], gf = gsh[t][1], gg = gsh[t][2], go = gsh[t][3];
        float c0 = hidden[nn];
        float c = sigf(gf) * c0 + sigf(gi) * tanhf(gg);
        float h = sigf(go) * tanhf(c);
        ws[WS_H + nn] = h;
        out[V + nn] = h;
        out[V + H + nn] = c;
    }
}

// kE: vocab logits + per-block exp-sum partial (plain store).
// grid 1280 x 256 = exactly 5 blocks/CU (no straggler tail).
// V = 1280*39 + 337: blocks < 337 take 40 rows.
__global__ __launch_bounds__(256) void kE_vocab(const float* __restrict__ out_W,
                                                const float* __restrict__ out_b,
                                                float* __restrict__ ws) {
    const int bid = blockIdx.x, t = threadIdx.x;
    const int w = t >> 6, l = t & 63;
    const int row0 = bid * 39 + (bid < 337 ? bid : 337);
    const int cnt  = 39 + (bid < 337 ? 1 : 0);

    const float4* h4 = (const float4*)(ws + WS_H);
    float4 hr[4];
#pragma unroll
    for (int i = 0; i < 4; ++i) hr[i] = h4[i * 64 + l];

    const float4* ow = (const float4*)out_W;
    float es = 0.f;
    int wq = (cnt + 3) >> 2;
    int kb = w * wq;
    int ke = kb + wq < cnt ? kb + wq : cnt;
    for (int k = kb; k < ke; k += 2) {
        bool has1 = (k + 1 < ke);
        int k1 = has1 ? k + 1 : k;
        int r0 = row0 + k, r1 = row0 + k1;
        const float4* q0 = ow + (size_t)r0 * 256;
        const float4* q1 = ow + (size_t)r1 * 256;
        float a0 = 0.f, a1 = 0.f;
#pragma unroll
        for (int i = 0; i < 4; ++i) {
            a0 += dot4(q0[i * 64 + l], hr[i]);
            a1 += dot4(q1[i * 64 + l], hr[i]);
        }
        float s0 = wave_sum(a0);
        float s1 = wave_sum(a1);
        if (l == 0) {
            float lg0 = s0 + out_b[r0];
            ws[WS_VLOG + r0] = lg0;
            es += expf(lg0);
            if (has1) {
                float lg1 = s1 + out_b[r1];
                ws[WS_VLOG + r1] = lg1;
                es += expf(lg1);
            }
        }
    }
    __shared__ float red[4];
    if (l == 0) red[w] = es;
    __syncthreads();
    if (t == 0) ws[WS_PART + bid] = red[0] + red[1] + red[2] + red[3];
}

// kF: redundant deterministic sum of 1280 partials (= 5*256 exact) + write
// own slice. grid 256 x 256 (1/CU). V = 256*196 + 81.
__global__ __launch_bounds__(256) void kF_logsoftmax(const float* __restrict__ ws,
                                                     float* __restrict__ out) {
    const int bid = blockIdx.x, t = threadIdx.x;
    float ps = 0.f;
#pragma unroll
    for (int k = 0; k < 5; ++k) ps += ws[WS_PART + k * 256 + t];
    float s = wave_sum(ps);
    __shared__ float red[4];
    __shared__ float lsh;
    if ((t & 63) == 0) red[t >> 6] = s;
    __syncthreads();
    if (t == 0) lsh = logf(red[0] + red[1] + red[2] + red[3]);
    __syncthreads();
    float lse = lsh;
    const int row0 = bid * 196 + (bid < 81 ? bid : 81);
    const int cnt  = 196 + (bid < 81 ? 1 : 0);
    for (int i = t; i < cnt; i += 256)
        out[row0 + i] = ws[WS_VLOG + row0 + i] - lse;
}

extern "C" void kernel_launch(void* const* d_in, const int* in_sizes, int n_in,
                              void* d_out, int out_size, void* d_ws, size_t ws_size,
                              hipStream_t stream) {
    const int*   tok     = (const int*)d_in[0];
    const float* hidden  = (const float*)d_in[1];
    const float* enc     = (const float*)d_in[2];
    const float* emb     = (const float*)d_in[3];
    const float* attn_W  = (const float*)d_in[4];
    const float* attn_b  = (const float*)d_in[5];
    const float* comb_W  = (const float*)d_in[6];
    const float* comb_b  = (const float*)d_in[7];
    const float* W_ih    = (const float*)d_in[8];
    const float* W_hh    = (const float*)d_in[9];
    const float* b_ih    = (const float*)d_in[10];
    const float* b_hh    = (const float*)d_in[11];
    const float* out_W   = (const float*)d_in[12];
    const float* out_b   = (const float*)d_in[13];
    float* out = (float*)d_out;
    float* ws  = (float*)d_ws;

    hipMemsetAsync(ws, 0, MEMSET_BYTES, stream);   // zero attn accumulator
    kAB<<<128, 256, 0, stream>>>(tok, hidden, enc, emb, attn_W, attn_b, ws);
    kC_combine<<<256, 256, 0, stream>>>(tok, emb, comb_W, comb_b, ws, out);
    kD_gates_lstm<<<512, 256, 0, stream>>>(hidden, W_ih, W_hh, b_ih, b_hh, ws, out);
    kE_vocab<<<1280, 256, 0, stream>>>(out_W, out_b, ws);
    kF_logsoftmax<<<256, 256, 0, stream>>>(ws, out);
}

// Round 8
// 60.202 us; speedup vs baseline: 21.1850x; 1.0204x over previous
//
#include <hip/hip_runtime.h>
#include <math.h>

#define H 1024
#define V 50257
#define L 512

// ws float indices
#define WS_ATTN  0      // 1024 unnormalized attn accum (atomicAdd; memset-zeroed)
#define WS_DEN   1024   // 64 denom partials (plain stores, unique writer)
#define WS_E     1088   // 512 unnormalized exp(logit)
#define WS_X     1600   // 1024 combine output
#define WS_H     2624   // 1024 new h
#define WS_VLOG  3648   // 50257 vocab logits
#define WS_PART  53905  // 2048 per-block vocab exp-sums
#define MEMSET_BYTES 4096   // zeroes WS_ATTN [0,1024)

__device__ __forceinline__ float wave_sum(float v) {
    for (int o = 32; o > 0; o >>= 1) v += __shfl_down(v, o, 64);
    return v;
}
__device__ __forceinline__ float sigf(float x) { return 1.0f / (1.0f + expf(-x)); }
__device__ __forceinline__ float dot4(float4 a, float4 b) {
    return a.x * b.x + a.y * b.y + a.z * b.z + a.w * b.w;
}

// kAB: fused attn logits + (no-max) softmax numerators + unnormalized
// attn_applied. grid 256 x 256; block = (jb = col quarter, c = 8-logit chunk).
// Full-chip: 1 block/CU. attn_W redundancy 4x (16 MB, ~L3/HBM 2.5 us).
// jb==0 blocks store e and the chunk denom partial (unique writers).
// atomicAdd: 65536 adds over 64 lines -> ~1 us tail (proven-safe regime).
__global__ __launch_bounds__(256) void kAB(const int* __restrict__ tok,
                                           const float* __restrict__ hidden,
                                           const float* __restrict__ enc,
                                           const float* __restrict__ emb,
                                           const float* __restrict__ attn_W,
                                           const float* __restrict__ attn_b,
                                           float* __restrict__ ws) {
    const int bid = blockIdx.x, t = threadIdx.x;
    const int w = t >> 6, l = t & 63;
    const int jb = bid >> 6, c = bid & 63;
    const size_t token = (size_t)tok[0];
    const float4* ev4 = (const float4*)(emb + token * H);
    const float4* hv4 = (const float4*)hidden;

    __shared__ float esh[8];

    // wave w computes logits r = c*8 + w*2 + {0,1} (pair ILP)
    {
        int r0 = c * 8 + w * 2;
        int r1 = r0 + 1;
        const float4* rw0 = (const float4*)(attn_W + (size_t)r0 * 2 * H);
        const float4* rw1 = (const float4*)(attn_W + (size_t)r1 * 2 * H);
        float a0 = 0.f, a1 = 0.f;
#pragma unroll
        for (int i = 0; i < 4; ++i) {
            float4 e4 = ev4[i * 64 + l], h4 = hv4[i * 64 + l];
            a0 += dot4(rw0[i * 64 + l], e4) + dot4(rw0[256 + i * 64 + l], h4);
            a1 += dot4(rw1[i * 64 + l], e4) + dot4(rw1[256 + i * 64 + l], h4);
        }
        float s0 = wave_sum(a0);
        float s1 = wave_sum(a1);
        if (l == 0) {
            esh[w * 2]     = expf(s0 + attn_b[r0]);
            esh[w * 2 + 1] = expf(s1 + attn_b[r1]);
        }
    }
    __syncthreads();
    if (jb == 0) {
        if (t < 8) ws[WS_E + c * 8 + t] = esh[t];
        if (t == 0) {
            float p = 0.f;
#pragma unroll
            for (int i = 0; i < 8; ++i) p += esh[i];
            ws[WS_DEN + c] = p;   // unique writer per c
        }
    }
    // unnormalized attn accumulate: 8 enc rows x this block's 256-col quarter
    int j = jb * 256 + t;
    float acc = 0.f;
#pragma unroll
    for (int i = 0; i < 8; ++i)
        acc += esh[i] * enc[(size_t)(c * 8 + i) * H + j];
    atomicAdd(&ws[WS_ATTN + j], acc);
}

// kC: S = sum of 64 denom partials (wave 0); x = relu(cwL@emb +
// (cwR@attn_unnorm)/S + b). Blocks 0,1 write attn_weights = e/S.
// grid 256 x 256, wave per row.
__global__ __launch_bounds__(256) void kC_combine(const int* __restrict__ tok,
                                                  const float* __restrict__ emb,
                                                  const float* __restrict__ comb_W,
                                                  const float* __restrict__ comb_b,
                                                  float* __restrict__ ws,
                                                  float* __restrict__ out) {
    const int bid = blockIdx.x, t = threadIdx.x;
    const int w = t >> 6, l = t & 63;
    __shared__ float Ssh;
    float dv = (t < 64) ? ws[WS_DEN + t] : 0.f;
    if (w == 0) {
        float s = wave_sum(dv);
        if (t == 0) Ssh = s;
    }
    __syncthreads();
    float invS = 1.0f / Ssh;

    if (bid < 2) out[V + 2 * H + bid * 256 + t] = ws[WS_E + bid * 256 + t] * invS;

    const size_t token = (size_t)tok[0];
    const float4* ev4 = (const float4*)(emb + token * H);
    const float4* a4 = (const float4*)(ws + WS_ATTN);
    int r = bid * 4 + w;
    const float4* cw = (const float4*)comb_W;
    float aL = 0.f, aR = 0.f;
#pragma unroll
    for (int i = 0; i < 4; ++i) {
        aL += dot4(cw[(size_t)r * 512 + i * 64 + l], ev4[i * 64 + l]);
        aR += dot4(cw[(size_t)r * 512 + 256 + i * 64 + l], a4[i * 64 + l]);
    }
    float s = wave_sum(aL + aR * invS);
    if (l == 0) ws[WS_X + r] = fmaxf(s + comb_b[r], 0.0f);
}

// kD: gates + LSTM pointwise. grid 1024 x 256: block = unit n, wave = gate.
// Full occupancy (4 blocks/CU), 32 KB weights per block.
__global__ __launch_bounds__(256) void kD_gates_lstm(const float* __restrict__ hidden,
                                                     const float* __restrict__ W_ih,
                                                     const float* __restrict__ W_hh,
                                                     const float* __restrict__ b_ih,
                                                     const float* __restrict__ b_hh,
                                                     float* __restrict__ ws,
                                                     float* __restrict__ out) {
    const int n = blockIdx.x, t = threadIdx.x;
    const int w = t >> 6, l = t & 63;
    __shared__ float4 xs[256], hs[256];
    __shared__ float gsh[4];
    xs[t] = ((const float4*)(ws + WS_X))[t];
    hs[t] = ((const float4*)hidden)[t];
    __syncthreads();
    int row = w * H + n;
    const float4* wi = (const float4*)W_ih;
    const float4* wh = (const float4*)W_hh;
    float acc = 0.f;
#pragma unroll
    for (int i = 0; i < 4; ++i) {
        acc += dot4(wi[(size_t)row * 256 + i * 64 + l], xs[i * 64 + l]);
        acc += dot4(wh[(size_t)row * 256 + i * 64 + l], hs[i * 64 + l]);
    }
    float s = wave_sum(acc);
    if (l == 0) gsh[w] = s + b_ih[row] + b_hh[row];
    __syncthreads();
    if (t == 0) {
        float c0 = hidden[n];
        float cc = sigf(gsh[1]) * c0 + sigf(gsh[0]) * tanhf(gsh[2]);
        float hh = sigf(gsh[3]) * tanhf(cc);
        ws[WS_H + n] = hh;
        out[V + n] = hh;
        out[V + H + n] = cc;
    }
}

// kE: vocab logits + per-block exp-sum partial (plain store).
// grid 2048 x 256 = exactly 8 blocks/CU (32 waves/CU, max occupancy).
// V = 2048*24 + 1105: blocks < 1105 take 25 rows.
__global__ __launch_bounds__(256) void kE_vocab(const float* __restrict__ out_W,
                                                const float* __restrict__ out_b,
                                                float* __restrict__ ws) {
    const int bid = blockIdx.x, t = threadIdx.x;
    const int w = t >> 6, l = t & 63;
    const int row0 = bid * 24 + (bid < 1105 ? bid : 1105);
    const int cnt  = 24 + (bid < 1105 ? 1 : 0);

    const float4* h4 = (const float4*)(ws + WS_H);
    float4 hr[4];
#pragma unroll
    for (int i = 0; i < 4; ++i) hr[i] = h4[i * 64 + l];

    const float4* ow = (const float4*)out_W;
    float es = 0.f;
    int wq = (cnt + 3) >> 2;
    int kb = w * wq;
    int ke = kb + wq < cnt ? kb + wq : cnt;
    for (int k = kb; k < ke; k += 2) {
        bool has1 = (k + 1 < ke);
        int k1 = has1 ? k + 1 : k;
        int r0 = row0 + k, r1 = row0 + k1;
        const float4* q0 = ow + (size_t)r0 * 256;
        const float4* q1 = ow + (size_t)r1 * 256;
        float a0 = 0.f, a1 = 0.f;
#pragma unroll
        for (int i = 0; i < 4; ++i) {
            a0 += dot4(q0[i * 64 + l], hr[i]);
            a1 += dot4(q1[i * 64 + l], hr[i]);
        }
        float s0 = wave_sum(a0);
        float s1 = wave_sum(a1);
        if (l == 0) {
            float lg0 = s0 + out_b[r0];
            ws[WS_VLOG + r0] = lg0;
            es += expf(lg0);
            if (has1) {
                float lg1 = s1 + out_b[r1];
                ws[WS_VLOG + r1] = lg1;
                es += expf(lg1);
            }
        }
    }
    __shared__ float red[4];
    if (l == 0) red[w] = es;
    __syncthreads();
    if (t == 0) ws[WS_PART + bid] = red[0] + red[1] + red[2] + red[3];
}

// kF: redundant deterministic sum of 2048 partials (= 8*256 exact) + write
// own slice. grid 256 x 256. V = 256*196 + 81.
__global__ __launch_bounds__(256) void kF_logsoftmax(const float* __restrict__ ws,
                                                     float* __restrict__ out) {
    const int bid = blockIdx.x, t = threadIdx.x;
    float ps = 0.f;
#pragma unroll
    for (int k = 0; k < 8; ++k) ps += ws[WS_PART + k * 256 + t];
    float s = wave_sum(ps);
    __shared__ float red[4];
    __shared__ float lsh;
    if ((t & 63) == 0) red[t >> 6] = s;
    __syncthreads();
    if (t == 0) lsh = logf(red[0] + red[1] + red[2] + red[3]);
    __syncthreads();
    float lse = lsh;
    const int row0 = bid * 196 + (bid < 81 ? bid : 81);
    const int cnt  = 196 + (bid < 81 ? 1 : 0);
    for (int i = t; i < cnt; i += 256)
        out[row0 + i] = ws[WS_VLOG + row0 + i] - lse;
}

extern "C" void kernel_launch(void* const* d_in, const int* in_sizes, int n_in,
                              void* d_out, int out_size, void* d_ws, size_t ws_size,
                              hipStream_t stream) {
    const int*   tok     = (const int*)d_in[0];
    const float* hidden  = (const float*)d_in[1];
    const float* enc     = (const float*)d_in[2];
    const float* emb     = (const float*)d_in[3];
    const float* attn_W  = (const float*)d_in[4];
    const float* attn_b  = (const float*)d_in[5];
    const float* comb_W  = (const float*)d_in[6];
    const float* comb_b  = (const float*)d_in[7];
    const float* W_ih    = (const float*)d_in[8];
    const float* W_hh    = (const float*)d_in[9];
    const float* b_ih    = (const float*)d_in[10];
    const float* b_hh    = (const float*)d_in[11];
    const float* out_W   = (const float*)d_in[12];
    const float* out_b   = (const float*)d_in[13];
    float* out = (float*)d_out;
    float* ws  = (float*)d_ws;

    hipMemsetAsync(ws, 0, MEMSET_BYTES, stream);   // zero attn accumulator
    kAB<<<256, 256, 0, stream>>>(tok, hidden, enc, emb, attn_W, attn_b, ws);
    kC_combine<<<256, 256, 0, stream>>>(tok, emb, comb_W, comb_b, ws, out);
    kD_gates_lstm<<<1024, 256, 0, stream>>>(hidden, W_ih, W_hh, b_ih, b_hh, ws, out);
    kE_vocab<<<2048, 256, 0, stream>>>(out_W, out_b, ws);
    kF_logsoftmax<<<256, 256, 0, stream>>>(ws, out);
}